// Round 1
// baseline (195.755 us; speedup 1.0000x reference)
//
#include <hip/hip_runtime.h>
#include <stdint.h>

#define D 128
#define TM 64           // rows per tile
#define GRID 512
#define NTHREADS 256

typedef float f32x4 __attribute__((ext_vector_type(4)));
typedef short s16x8 __attribute__((ext_vector_type(8)));

__device__ __forceinline__ short f2bf(float f) {
    union { float f; uint32_t u; } v; v.f = f;
    uint32_t u = v.u;
    uint32_t r = (u + 0x7fffu + ((u >> 16) & 1u)) >> 16;   // RNE
    return (short)r;
}

__global__ __launch_bounds__(NTHREADS, 2)
void gate_agg_kernel(const float* __restrict__ X,
                     const int* __restrict__ bidx,
                     const float* __restrict__ W1,
                     const float* __restrict__ b1,
                     const float* __restrict__ W2,
                     const float* __restrict__ b2,
                     float* __restrict__ out,
                     int NT)
{
    __shared__ short w1p[16 * D * 8];      // bf16 B-frags: [k>>3][n][k&7], 32KB
    __shared__ float xtile[TM * D];        // fp32, 16B-chunk XOR-swizzled, 32KB
    __shared__ float gateL[TM];
    __shared__ int   idxL[TM];

    const int tid = threadIdx.x;
    const int l = tid & 63;
    const int w = tid >> 6;

    // ---- one-time: pack W1 (fp32 row-major [k][n]) -> bf16 LDS [k>>3][n][k&7]
    for (int i = tid; i < D * D; i += NTHREADS) {
        int k = i >> 7, n = i & 127;
        w1p[(((k >> 3) * D) + n) * 8 + (k & 7)] = f2bf(W1[i]);
    }

    // per-lane b1/W2 for cols ct*16 + (l&15)   (same every tile)
    float b1v[8], w2v[8];
    #pragma unroll
    for (int ct = 0; ct < 8; ++ct) {
        b1v[ct] = b1[ct * 16 + (l & 15)];
        w2v[ct] = W2[ct * 16 + (l & 15)];
    }
    const float b2s = b2[0];

    // balanced contiguous tile range for this block
    const int q = NT / GRID, rem = NT % GRID;
    int t0, t1;
    if ((int)blockIdx.x < rem) { t0 = blockIdx.x * (q + 1); t1 = t0 + q + 1; }
    else { t0 = rem * (q + 1) + ((int)blockIdx.x - rem) * q; t1 = t0 + q; }

    // phase-3 persistent per-thread state: thread owns (col c, row-half)
    const int c = tid & 127;
    const int half = tid >> 7;
    float acc3 = 0.0f;
    int cur = -1;

    __syncthreads();   // w1p ready

    for (int t = t0; t < t1; ++t) {
        const float* xg = X + (size_t)t * TM * D;

        // ---- stage X tile -> LDS with chunk16 ^= (row&15) swizzle ----
        f32x4 v[8];
        #pragma unroll
        for (int j = 0; j < 8; ++j) {
            int qc = j * 256 + tid;                       // 16B-chunk id, 2048 total
            v[j] = *(const f32x4*)((const char*)xg + (size_t)qc * 16);
        }
        #pragma unroll
        for (int j = 0; j < 8; ++j) {
            int qc = j * 256 + tid;
            int row = qc >> 5, c16 = qc & 31;
            *(f32x4*)((char*)xtile + row * 512 + ((c16 ^ (row & 15)) << 4)) = v[j];
        }
        if (tid < TM) idxL[tid] = bidx[(size_t)t * TM + tid];
        __syncthreads();

        // ---- phase 1: h = relu(X@W1 + b1), 16 rows per wave via MFMA ----
        f32x4 acc[8];
        #pragma unroll
        for (int ct = 0; ct < 8; ++ct) acc[ct] = (f32x4)0.0f;

        const int rowA = w * 16 + (l & 15);
        #pragma unroll
        for (int kt = 0; kt < 4; ++kt) {
            const int c16a = kt * 8 + 2 * (l >> 4);
            f32x4 xa = *(const f32x4*)((const char*)xtile + rowA * 512 + ((c16a ^ (l & 15)) << 4));
            f32x4 xb = *(const f32x4*)((const char*)xtile + rowA * 512 + (((c16a + 1) ^ (l & 15)) << 4));
            s16x8 a;
            a[0] = f2bf(xa[0]); a[1] = f2bf(xa[1]); a[2] = f2bf(xa[2]); a[3] = f2bf(xa[3]);
            a[4] = f2bf(xb[0]); a[5] = f2bf(xb[1]); a[6] = f2bf(xb[2]); a[7] = f2bf(xb[3]);
            #pragma unroll
            for (int ct = 0; ct < 8; ++ct) {
                s16x8 bfr = *(const s16x8*)&w1p[((kt * 4 + (l >> 4)) * D + ct * 16 + (l & 15)) * 8];
                acc[ct] = __builtin_amdgcn_mfma_f32_16x16x32_bf16(a, bfr, acc[ct], 0, 0, 0);
            }
        }

        // ---- phase 2: logit = h . W2, sigmoid ----
        float p[4] = {0.0f, 0.0f, 0.0f, 0.0f};
        #pragma unroll
        for (int ct = 0; ct < 8; ++ct) {
            #pragma unroll
            for (int r = 0; r < 4; ++r) {
                float h = acc[ct][r] + b1v[ct];
                h = fmaxf(h, 0.0f);
                p[r] = fmaf(h, w2v[ct], p[r]);
            }
        }
        #pragma unroll
        for (int r = 0; r < 4; ++r) {
            #pragma unroll
            for (int m = 1; m < 16; m <<= 1) p[r] += __shfl_xor(p[r], m, 64);
        }
        if ((l & 15) == 0) {
            #pragma unroll
            for (int r = 0; r < 4; ++r) {
                float g = 1.0f / (1.0f + __expf(-(p[r] + b2s)));
                gateL[w * 16 + (l >> 4) * 4 + r] = g;
            }
        }
        __syncthreads();

        // ---- phase 3: segmented accumulate of gate*x (fp32 X from LDS) ----
        #pragma unroll 8
        for (int rr = 0; rr < 32; ++rr) {
            int r = half * 32 + rr;
            int seg = idxL[r];
            float g = gateL[r];
            if (seg != cur) {                        // wave-uniform branch
                if (cur >= 0) atomicAdd(out + (size_t)cur * D + c, acc3);
                acc3 = 0.0f; cur = seg;
            }
            float xv = *(const float*)((const char*)xtile + r * 512 +
                        ((((c >> 2) ^ (r & 15)) << 4)) + (c & 3) * 4);
            acc3 = fmaf(g, xv, acc3);
        }
        __syncthreads();   // protect xtile/gateL/idxL before next stage
    }
    if (cur >= 0) atomicAdd(out + (size_t)cur * D + c, acc3);
}

extern "C" void kernel_launch(void* const* d_in, const int* in_sizes, int n_in,
                              void* d_out, int out_size, void* d_ws, size_t ws_size,
                              hipStream_t stream) {
    const float* X    = (const float*)d_in[0];
    const int*   bidx = (const int*)d_in[1];
    const float* W1   = (const float*)d_in[2];
    const float* b1   = (const float*)d_in[3];
    const float* W2   = (const float*)d_in[4];
    const float* b2   = (const float*)d_in[5];
    float* out = (float*)d_out;

    const int N  = in_sizes[0] / D;      // 1,000,000
    const int NT = N / TM;               // 15,625 tiles (exact)

    hipMemsetAsync(d_out, 0, (size_t)out_size * sizeof(float), stream);
    gate_agg_kernel<<<GRID, NTHREADS, 0, stream>>>(X, bidx, W1, b1, W2, b2, out, NT);
}

// Round 2
// 121.968 us; speedup vs baseline: 1.6050x; 1.6050x over previous
//
#include <hip/hip_runtime.h>
#include <stdint.h>

#define D 128
#define TM 64           // rows per tile
#define GRID 768        // 3 blocks/CU * 256 CU
#define NTHREADS 256

typedef float f32x4 __attribute__((ext_vector_type(4)));
typedef short s16x8 __attribute__((ext_vector_type(8)));
typedef uint32_t u32x2 __attribute__((ext_vector_type(2)));

__device__ __forceinline__ uint32_t f2bf_u(float f) {
    union { float f; uint32_t u; } v; v.f = f;
    return (v.u + 0x7fffu + ((v.u >> 16) & 1u)) >> 16;   // RNE
}
__device__ __forceinline__ short f2bf(float f) { return (short)f2bf_u(f); }
__device__ __forceinline__ float bf2f(uint32_t us) {
    union { uint32_t u; float f; } v; v.u = us << 16; return v.f;
}
__device__ __forceinline__ uint32_t cvt_pk_bf16(float lo, float hi) {
    uint32_t r;
    asm("v_cvt_pk_bf16_f32 %0, %1, %2" : "=v"(r) : "v"(lo), "v"(hi));
    return r;
}

__global__ __launch_bounds__(NTHREADS, 3)
void gate_agg_kernel(const float* __restrict__ X,
                     const int* __restrict__ bidx,
                     const float* __restrict__ W1,
                     const float* __restrict__ b1,
                     const float* __restrict__ W2,
                     const float* __restrict__ b2,
                     float* __restrict__ out,
                     int NT)
{
    __shared__ short w1p[16 * D * 8];      // bf16 B-frags [k>>3][n][k&7], 32 KB
    __shared__ short xtile[TM * D];        // bf16, 16B-chunk XOR-swizzled, 16 KB
    __shared__ float gateL[TM];
    __shared__ int   idxL[TM];

    const int tid = threadIdx.x;
    const int l = tid & 63;
    const int w = tid >> 6;

    // ---- one-time: pack W1 (fp32 row-major [k][n]) -> bf16 LDS [k>>3][n][k&7]
    for (int i = tid; i < D * D; i += NTHREADS) {
        int k = i >> 7, n = i & 127;
        w1p[(((k >> 3) * D) + n) * 8 + (k & 7)] = f2bf(W1[i]);
    }

    // per-lane b1/W2 for cols ct*16 + (l&15)
    float b1v[8], w2v[8];
    #pragma unroll
    for (int ct = 0; ct < 8; ++ct) {
        b1v[ct] = b1[ct * 16 + (l & 15)];
        w2v[ct] = W2[ct * 16 + (l & 15)];
    }
    const float b2s = b2[0];

    // balanced contiguous tile range
    const int q = NT / GRID, rem = NT % GRID;
    int t0, t1;
    if ((int)blockIdx.x < rem) { t0 = blockIdx.x * (q + 1); t1 = t0 + q + 1; }
    else { t0 = rem * (q + 1) + ((int)blockIdx.x - rem) * q; t1 = t0 + q; }

    // phase-3 persistent state: thread owns (col c, row-half)
    const int c = tid & 127;
    const int half = tid >> 7;
    float acc3 = 0.0f;
    int cur = -1;

    // ---- prologue: prefetch tile t0 into registers
    f32x4 v[8];
    int ridx = 0;
    if (t0 < t1) {
        const float* xg = X + (size_t)t0 * TM * D;
        #pragma unroll
        for (int j = 0; j < 8; ++j)
            v[j] = *(const f32x4*)(xg + (size_t)(j * 256 + tid) * 4);
        if (tid < TM) ridx = bidx[(size_t)t0 * TM + tid];
    }

    __syncthreads();   // w1p ready

    for (int t = t0; t < t1; ++t) {
        // ---- stage: convert held registers -> bf16 swizzled LDS ----
        #pragma unroll
        for (int j = 0; j < 8; ++j) {
            int qc = j * 256 + tid;                 // 16B-f32-chunk id
            int row = qc >> 5, cq = qc & 31;        // 32 f32-chunks per row
            int cc = cq >> 1, h = cq & 1;           // bf16 16B-chunk + half
            u32x2 wv;
            wv[0] = cvt_pk_bf16(v[j][0], v[j][1]);
            wv[1] = cvt_pk_bf16(v[j][2], v[j][3]);
            *(u32x2*)((char*)xtile + row * 256 + ((cc ^ (row & 15)) << 4) + h * 8) = wv;
        }
        if (tid < TM) idxL[tid] = ridx;
        __syncthreads();

        // ---- T14: issue next tile's global loads NOW (overlap phases 1-3)
        if (t + 1 < t1) {
            const float* xg = X + (size_t)(t + 1) * TM * D;
            #pragma unroll
            for (int j = 0; j < 8; ++j)
                v[j] = *(const f32x4*)(xg + (size_t)(j * 256 + tid) * 4);
            if (tid < TM) ridx = bidx[(size_t)(t + 1) * TM + tid];
        }

        // ---- phase 1: h = relu(X@W1 + b1), 16 rows per wave via MFMA ----
        f32x4 acc[8];
        #pragma unroll
        for (int ct = 0; ct < 8; ++ct) acc[ct] = (f32x4)0.0f;

        const int rowA = w * 16 + (l & 15);
        const char* rbase = (const char*)xtile + rowA * 256;
        #pragma unroll
        for (int kt = 0; kt < 4; ++kt) {
            const int kc = kt * 4 + (l >> 4);
            s16x8 a = *(const s16x8*)(rbase + ((kc ^ (rowA & 15)) << 4));
            #pragma unroll
            for (int ct = 0; ct < 8; ++ct) {
                s16x8 bfr = *(const s16x8*)&w1p[((kt * 4 + (l >> 4)) * D + ct * 16 + (l & 15)) * 8];
                acc[ct] = __builtin_amdgcn_mfma_f32_16x16x32_bf16(a, bfr, acc[ct], 0, 0, 0);
            }
        }

        // ---- phase 2: logit = h . W2, sigmoid -> gateL ----
        float p[4] = {0.0f, 0.0f, 0.0f, 0.0f};
        #pragma unroll
        for (int ct = 0; ct < 8; ++ct) {
            #pragma unroll
            for (int r = 0; r < 4; ++r) {
                float h = acc[ct][r] + b1v[ct];
                h = fmaxf(h, 0.0f);
                p[r] = fmaf(h, w2v[ct], p[r]);
            }
        }
        #pragma unroll
        for (int r = 0; r < 4; ++r) {
            #pragma unroll
            for (int m = 1; m < 16; m <<= 1) p[r] += __shfl_xor(p[r], m, 64);
        }
        if ((l & 15) == 0) {
            #pragma unroll
            for (int r = 0; r < 4; ++r) {
                float g = 1.0f / (1.0f + __expf(-(p[r] + b2s)));
                gateL[w * 16 + (l >> 4) * 4 + r] = g;
            }
        }
        __syncthreads();

        // ---- phase 3: segmented accumulate of gate*x (bf16 X from LDS) ----
        #pragma unroll 8
        for (int rr = 0; rr < 32; ++rr) {
            int r = half * 32 + rr;
            int seg = idxL[r];
            float g = gateL[r];
            if (seg != cur) {                        // wave-uniform branch
                if (cur >= 0) atomicAdd(out + (size_t)cur * D + c, acc3);
                acc3 = 0.0f; cur = seg;
            }
            uint32_t xv = *(const uint16_t*)((const char*)xtile + r * 256 +
                           (((c >> 3) ^ (r & 15)) << 4) + (c & 7) * 2);
            acc3 = fmaf(g, bf2f(xv), acc3);
        }
        __syncthreads();   // protect xtile/gateL/idxL before next stage
    }
    if (cur >= 0) atomicAdd(out + (size_t)cur * D + c, acc3);
}

extern "C" void kernel_launch(void* const* d_in, const int* in_sizes, int n_in,
                              void* d_out, int out_size, void* d_ws, size_t ws_size,
                              hipStream_t stream) {
    const float* X    = (const float*)d_in[0];
    const int*   bidx = (const int*)d_in[1];
    const float* W1   = (const float*)d_in[2];
    const float* b1   = (const float*)d_in[3];
    const float* W2   = (const float*)d_in[4];
    const float* b2   = (const float*)d_in[5];
    float* out = (float*)d_out;

    const int N  = in_sizes[0] / D;      // 1,000,000
    const int NT = N / TM;               // 15,625 tiles (exact)

    hipMemsetAsync(d_out, 0, (size_t)out_size * sizeof(float), stream);
    gate_agg_kernel<<<GRID, NTHREADS, 0, stream>>>(X, bidx, W1, b1, W2, b2, out, NT);
}